// Round 5
// baseline (221.537 us; speedup 1.0000x reference)
//
#include <hip/hip_runtime.h>
#include <math.h>

#define N 4096
#define IN_F 256
#define OUT_F 64
#define HEADS 4
#define NEG 0.2f
#define JSPLIT 8
#define JLEN (N / JSPLIT)        // 512
#define NC (JLEN / 32)           // 16 chunks
#define LOG2E 1.44269504088896f

typedef float f32x4 __attribute__((ext_vector_type(4)));
typedef short short8 __attribute__((ext_vector_type(8)));

#define FMA4S(A, s, V) do { (A).x = fmaf((s),(V).x,(A).x); (A).y = fmaf((s),(V).y,(A).y); \
                            (A).z = fmaf((s),(V).z,(A).z); (A).w = fmaf((s),(V).w,(A).w); } while(0)

__device__ __forceinline__ unsigned short f2bf(float x) {
  unsigned int u = __float_as_uint(x);
  u += 0x7fffu + ((u >> 16) & 1u);   // RNE
  return (unsigned short)(u >> 16);
}

__device__ __forceinline__ float exp2_fast(float x) {
#if __has_builtin(__builtin_amdgcn_exp2f)
  return __builtin_amdgcn_exp2f(x);
#else
  return exp2f(x);
#endif
}

// pack bf16(p1)<<16 | bf16(p0), round-half-up
__device__ __forceinline__ int pack_bf2(float p0, float p1) {
  unsigned u0 = __float_as_uint(p0) + 0x8000u;
  unsigned u1 = __float_as_uint(p1) + 0x8000u;
  return (int)__builtin_amdgcn_perm(u1, u0, 0x07060302u);
}

// ---------------------------------------------------------------------------
// Kernel 1: xt = x @ W[h] for a 16-row tile. grid (256, 4), block 256.
// Emits src/dst (log2e-scaled) and xtB (bf16 MFMA B-fragment layout).
// ---------------------------------------------------------------------------
__global__ __launch_bounds__(256) void k_xt(const float* __restrict__ x,
                                            const float* __restrict__ W,
                                            const float* __restrict__ a,
                                            short* __restrict__ xtB,
                                            float* __restrict__ src,
                                            float* __restrict__ dst) {
  __shared__ __align__(16) float xls[16 * 260];   // 16 rows x 65 float4
  const int t  = threadIdx.x;
  const int h  = blockIdx.y;
  const int bx = blockIdx.x;
  const int i0 = bx * 16;
  const int fg = t & 15;
  const int rg = t >> 4;

  const float4* xg = (const float4*)x;
  float4* xls4 = (float4*)xls;
  #pragma unroll
  for (int s = 0; s < 4; ++s) {
    int idx = t + 256 * s;
    int row = idx >> 6, c4 = idx & 63;
    xls4[row * 65 + c4] = xg[(size_t)(i0 + row) * 64 + c4];
  }
  __syncthreads();

  float4 acc = make_float4(0.f, 0.f, 0.f, 0.f);
  const float4* wg4 = (const float4*)W + (size_t)h * 4096;
  const float4* xr4 = (const float4*)xls + rg * 65;

  #pragma unroll 4
  for (int kk = 0; kk < 256; kk += 4) {
    float4 wv0 = wg4[(kk + 0) * 16 + fg];
    float4 wv1 = wg4[(kk + 1) * 16 + fg];
    float4 wv2 = wg4[(kk + 2) * 16 + fg];
    float4 wv3 = wg4[(kk + 3) * 16 + fg];
    float4 xv  = xr4[kk >> 2];
    FMA4S(acc, xv.x, wv0);
    FMA4S(acc, xv.y, wv1);
    FMA4S(acc, xv.z, wv2);
    FMA4S(acc, xv.w, wv3);
  }

  const float4* a4 = (const float4*)a;
  float4 as = a4[h * 32 + fg];
  float4 ad = a4[h * 32 + 16 + fg];
  float s_ = (acc.x * as.x + acc.y * as.y + acc.z * as.z + acc.w * as.w) * LOG2E;
  float d_ = (acc.x * ad.x + acc.y * ad.y + acc.z * ad.z + acc.w * ad.w) * LOG2E;
  #pragma unroll
  for (int off = 1; off < 16; off <<= 1) {
    s_ += __shfl_xor(s_, off, 64);
    d_ += __shfl_xor(d_, off, 64);
  }
  if (fg == 0) {
    src[h * N + i0 + rg] = s_;
    dst[h * N + i0 + rg] = d_;
  }

  __syncthreads();
  *(float4*)&xls[rg * 68 + fg * 4] = acc;
  __syncthreads();

  {
    const int lane = t & 63;
    const int g    = t >> 6;
    const int q    = lane >> 4;
    const int m    = lane & 15;
    if ((q >> 1) == (bx & 1)) {
      int jc = bx >> 1;
      short8 bv;
      #pragma unroll
      for (int r = 0; r < 8; ++r) {
        bv[r] = (short)f2bf(xls[((q & 1) * 8 + r) * 68 + g * 16 + m]);
      }
      ((short8*)xtB)[((size_t)(h * 128 + jc) * 4 + g) * 64 + lane] = bv;
    }
  }
}

// ---------------------------------------------------------------------------
// Kernel 2: fused flash PV. grid (128, JSPLIT=8), block 256 (wave = head).
// 2-stage pipeline, prefetch distance 2 for adj + B-frags. Row sums via a
// ones-B MFMA (idle matrix pipe) instead of VALU adds. No atomics.
// ---------------------------------------------------------------------------
__global__ __launch_bounds__(256, 4) void k_flash(const int* __restrict__ adj,
                                                  const float* __restrict__ src,
                                                  const float* __restrict__ dst,
                                                  const short* __restrict__ xtB,
                                                  float* __restrict__ accP,
                                                  float* __restrict__ lP) {
  __shared__ __align__(16) float dls[HEADS][JLEN + 4];
  const int t    = threadIdx.x;
  const int lane = t & 63;
  const int h    = t >> 6;
  const int i0   = blockIdx.x * 32;
  const int js   = blockIdx.y;
  const int q    = lane >> 4;
  const int m    = lane & 15;
  const int koff = q * 8;
  const int jbase = js * JLEN;

  // stage dst slice: 4 heads x JLEN floats = 512 f4, 2 per thread
  #pragma unroll
  for (int s = 0; s < 2; ++s) {
    int idx = t + 256 * s;            // 0..511
    int hh = idx >> 7, j4 = idx & 127;
    *(float4*)&dls[hh][j4 * 4] = *(const float4*)(dst + (size_t)hh * N + jbase + j4 * 4);
  }

  float sv = (lane < 32) ? src[h * N + i0 + lane] : 0.f;
  const float s0 = __shfl(sv, m, 64);
  const float s1 = __shfl(sv, 16 + m, 64);
  __syncthreads();

  f32x4 acc0[4], acc1[4], accL0, accL1;
  #pragma unroll
  for (int g = 0; g < 4; ++g) { acc0[g] = (f32x4)(0.f); acc1[g] = (f32x4)(0.f); }
  accL0 = (f32x4)(0.f);
  accL1 = (f32x4)(0.f);

  const unsigned short one_bf = 0x3F80;
  short8 ones;
  #pragma unroll
  for (int r = 0; r < 8; ++r) ones[r] = (short)one_bf;

  const int* arow0 = adj + (size_t)(i0 + m) * N + jbase + koff;
  const int* arow1 = adj + (size_t)(i0 + 16 + m) * N + jbase + koff;
  const short8* xbb = (const short8*)xtB + ((size_t)(h * 128 + js * NC) * 4) * 64 + lane;

#define LOADA(DA, CIDX) do {                                               \
    const int* r0_ = arow0 + (CIDX) * 32;                                  \
    const int* r1_ = arow1 + (CIDX) * 32;                                  \
    DA[0] = *(const int4*)r0_;  DA[1] = *(const int4*)(r0_ + 4);           \
    DA[2] = *(const int4*)r1_;  DA[3] = *(const int4*)(r1_ + 4);           \
  } while (0)
#define LOADB(DB, CIDX) do {                                               \
    const short8* bb_ = xbb + (size_t)(CIDX) * 256;                        \
    DB[0] = bb_[0]; DB[1] = bb_[64]; DB[2] = bb_[128]; DB[3] = bb_[192];   \
  } while (0)

#define COMPUTE(CA, CB, C) do {                                            \
    const float* dp_ = &dls[h][(C) * 32 + koff];                           \
    union { float4 v[2]; float f[8]; } du;                                 \
    du.v[0] = *(const float4*)dp_;                                         \
    du.v[1] = *(const float4*)(dp_ + 4);                                   \
    const int* a0i = (const int*)&CA[0];                                   \
    const int* a1i = (const int*)&CA[2];                                   \
    int av0[4], av1[4];                                                    \
    _Pragma("unroll")                                                      \
    for (int r2 = 0; r2 < 4; ++r2) {                                       \
      float e, el, p0a, p0b, p1a, p1b;                                     \
      e = s0 + du.f[2 * r2];     el = fmaxf(e, NEG * e);                   \
      el = (a0i[2 * r2] > 0) ? el : -1e30f;      p0a = exp2_fast(el);      \
      e = s0 + du.f[2 * r2 + 1]; el = fmaxf(e, NEG * e);                   \
      el = (a0i[2 * r2 + 1] > 0) ? el : -1e30f;  p0b = exp2_fast(el);      \
      e = s1 + du.f[2 * r2];     el = fmaxf(e, NEG * e);                   \
      el = (a1i[2 * r2] > 0) ? el : -1e30f;      p1a = exp2_fast(el);      \
      e = s1 + du.f[2 * r2 + 1]; el = fmaxf(e, NEG * e);                   \
      el = (a1i[2 * r2 + 1] > 0) ? el : -1e30f;  p1b = exp2_fast(el);      \
      av0[r2] = pack_bf2(p0a, p0b);                                        \
      av1[r2] = pack_bf2(p1a, p1b);                                        \
    }                                                                      \
    short8 af0 = __builtin_bit_cast(short8, *(int4*)av0);                  \
    short8 af1 = __builtin_bit_cast(short8, *(int4*)av1);                  \
    acc0[0] = __builtin_amdgcn_mfma_f32_16x16x32_bf16(af0, CB[0], acc0[0], 0, 0, 0); \
    acc0[1] = __builtin_amdgcn_mfma_f32_16x16x32_bf16(af0, CB[1], acc0[1], 0, 0, 0); \
    acc0[2] = __builtin_amdgcn_mfma_f32_16x16x32_bf16(af0, CB[2], acc0[2], 0, 0, 0); \
    acc0[3] = __builtin_amdgcn_mfma_f32_16x16x32_bf16(af0, CB[3], acc0[3], 0, 0, 0); \
    accL0   = __builtin_amdgcn_mfma_f32_16x16x32_bf16(af0, ones,  accL0,   0, 0, 0); \
    acc1[0] = __builtin_amdgcn_mfma_f32_16x16x32_bf16(af1, CB[0], acc1[0], 0, 0, 0); \
    acc1[1] = __builtin_amdgcn_mfma_f32_16x16x32_bf16(af1, CB[1], acc1[1], 0, 0, 0); \
    acc1[2] = __builtin_amdgcn_mfma_f32_16x16x32_bf16(af1, CB[2], acc1[2], 0, 0, 0); \
    acc1[3] = __builtin_amdgcn_mfma_f32_16x16x32_bf16(af1, CB[3], acc1[3], 0, 0, 0); \
    accL1   = __builtin_amdgcn_mfma_f32_16x16x32_bf16(af1, ones,  accL1,   0, 0, 0); \
  } while (0)

  int4   A[2][4];
  short8 B[2][4];
  LOADA(A[0], 0); LOADB(B[0], 0);
  LOADA(A[1], 1); LOADB(B[1], 1);

  for (int c = 0; c < NC; c += 2) {
    COMPUTE(A[0], B[0], c);
    {
      int cn = (c + 2 < NC) ? c + 2 : NC - 1;
      LOADA(A[0], cn); LOADB(B[0], cn);
    }
    COMPUTE(A[1], B[1], c + 1);
    {
      int cn = (c + 3 < NC) ? c + 3 : NC - 1;
      LOADA(A[1], cn); LOADB(B[1], cn);
    }
  }
#undef LOADA
#undef LOADB
#undef COMPUTE

  // ---- epilogue: plain stores into js-partial buffers ----
  // accL: row sums replicated across all 16 cols; row = q*4+reg.
  float* lp = lP + (size_t)js * (HEADS * N);
  if (m == 0) {
    #pragma unroll
    for (int reg = 0; reg < 4; ++reg) {
      lp[h * N + i0 + q * 4 + reg] = accL0[reg];
      lp[h * N + i0 + 16 + q * 4 + reg] = accL1[reg];
    }
  }

  float* ap = accP + (size_t)js * ((size_t)HEADS * N * OUT_F);
  #pragma unroll
  for (int reg = 0; reg < 4; ++reg) {
    int row0 = i0 + q * 4 + reg;
    int row1 = row0 + 16;
    #pragma unroll
    for (int g = 0; g < 4; ++g) {
      ap[((size_t)h * N + row0) * 64 + g * 16 + m] = acc0[g][reg];
      ap[((size_t)h * N + row1) * 64 + g * 16 + m] = acc1[g][reg];
    }
  }
}

// ---------------------------------------------------------------------------
// Kernel 3: out[i][h*64+f] = sum_js accP / sum_js lP
// ---------------------------------------------------------------------------
__global__ __launch_bounds__(256) void k_div(const float* __restrict__ accP,
                                             const float* __restrict__ lP,
                                             float* __restrict__ out) {
  int v = blockIdx.x * 256 + threadIdx.x;
  int col4 = v & 63;
  int i    = v >> 6;
  int h    = col4 >> 4;
  int fg   = col4 & 15;
  float4 s = make_float4(0.f, 0.f, 0.f, 0.f);
  float ls = 0.f;
  #pragma unroll
  for (int js = 0; js < JSPLIT; ++js) {
    const float4* a4p = (const float4*)(accP + (size_t)js * ((size_t)HEADS * N * OUT_F));
    float4 av = a4p[((size_t)h * N + i) * 16 + fg];
    s.x += av.x; s.y += av.y; s.z += av.z; s.w += av.w;
    ls += lP[(size_t)js * (HEADS * N) + h * N + i];
  }
  float il = 1.f / ls;
  ((float4*)out)[v] = make_float4(s.x * il, s.y * il, s.z * il, s.w * il);
}

extern "C" void kernel_launch(void* const* d_in, const int* in_sizes, int n_in,
                              void* d_out, int out_size, void* d_ws, size_t ws_size,
                              hipStream_t stream) {
  const float* x   = (const float*)d_in[0];
  const float* W   = (const float*)d_in[1];
  const float* a   = (const float*)d_in[2];
  const int*   adj = (const int*)d_in[3];
  float* out = (float*)d_out;

  float* ws   = (float*)d_ws;
  short* xtB  = (short*)ws;                                 // 2 MB
  float* src  = ws + 524288;                                // H*N
  float* dst  = src + HEADS * N;                            // H*N
  float* accP = dst + HEADS * N;                            // JSPLIT*H*N*64 = 33.5 MB
  float* lP   = accP + (size_t)JSPLIT * HEADS * N * OUT_F;  // JSPLIT*H*N

  k_xt<<<dim3(256, 4), 256, 0, stream>>>(x, W, a, xtB, src, dst);
  k_flash<<<dim3(N / 32, JSPLIT), 256, 0, stream>>>(adj, src, dst, xtB, accP, lP);
  k_div<<<dim3((N * OUT_F) / 256), 256, 0, stream>>>(accP, lP, out);
}

// Round 6
// 157.017 us; speedup vs baseline: 1.4109x; 1.4109x over previous
//
#include <hip/hip_runtime.h>
#include <math.h>

#define N 4096
#define IN_F 256
#define OUT_F 64
#define HEADS 4
#define NEG 0.2f
#define JSPLIT 8
#define JLEN (N / JSPLIT)        // 512
#define NC (JLEN / 32)           // 16 chunks
#define LOG2E 1.44269504088896f

typedef float f32x4 __attribute__((ext_vector_type(4)));
typedef short short8 __attribute__((ext_vector_type(8)));

#define FMA4S(A, s, V) do { (A).x = fmaf((s),(V).x,(A).x); (A).y = fmaf((s),(V).y,(A).y); \
                            (A).z = fmaf((s),(V).z,(A).z); (A).w = fmaf((s),(V).w,(A).w); } while(0)

__device__ __forceinline__ unsigned short f2bf(float x) {
  unsigned int u = __float_as_uint(x);
  u += 0x7fffu + ((u >> 16) & 1u);   // RNE
  return (unsigned short)(u >> 16);
}

__device__ __forceinline__ float exp2_fast(float x) {
#if __has_builtin(__builtin_amdgcn_exp2f)
  return __builtin_amdgcn_exp2f(x);
#else
  return exp2f(x);
#endif
}

// pack bf16(p1)<<16 | bf16(p0), round-half-up
__device__ __forceinline__ int pack_bf2(float p0, float p1) {
  unsigned u0 = __float_as_uint(p0) + 0x8000u;
  unsigned u1 = __float_as_uint(p1) + 0x8000u;
  return (int)__builtin_amdgcn_perm(u1, u0, 0x07060302u);
}

// ---------------------------------------------------------------------------
// Kernel 1: xt = x @ W[h], 64-row tile per block, grid (64,4), block 256.
// W[h] staged through LDS in 4 k-stages (read ONCE per block from global:
// 16 MB aggregate vs ~1 GB for the per-rg streaming variant). 4x4 register
// tile per thread. Emits src/dst (log2e-scaled) + xtB (bf16 B-frag layout).
// ---------------------------------------------------------------------------
__global__ __launch_bounds__(256) void k_xt(const float* __restrict__ x,
                                            const float* __restrict__ W,
                                            const float* __restrict__ a,
                                            short* __restrict__ xtB,
                                            float* __restrict__ src,
                                            float* __restrict__ dst) {
  __shared__ __align__(16) float xls[64 * 68];  // x tile, stride 68 floats
  __shared__ __align__(16) float wls[64 * 64];  // W k-slice
  const int t  = threadIdx.x;
  const int h  = blockIdx.y;
  const int i0 = blockIdx.x * 64;
  const int fg = t & 15;
  const int rg = t >> 4;

  float4 acc[4];
  acc[0] = acc[1] = acc[2] = acc[3] = make_float4(0.f, 0.f, 0.f, 0.f);

  const float4* xg = (const float4*)x;
  const float4* wg = (const float4*)W;
  float4* xls4 = (float4*)xls;
  float4* wls4 = (float4*)wls;
  const float4* xr4 = (const float4*)xls;
  const float4* wr4 = (const float4*)wls;

  for (int kt = 0; kt < 4; ++kt) {
    __syncthreads();
    // stage x tile slice: 64 rows x 64 k
    #pragma unroll
    for (int s = 0; s < 4; ++s) {
      int f4i = t + 256 * s;
      int row = f4i >> 4, c4 = f4i & 15;
      xls4[row * 17 + c4] = xg[(size_t)(i0 + row) * 64 + kt * 16 + c4];
    }
    // stage W slice: 64 k x 64 f (contiguous in W[h])
    #pragma unroll
    for (int s = 0; s < 4; ++s) {
      int f4i = t + 256 * s;
      int kk = f4i >> 4, c4 = f4i & 15;
      wls4[kk * 16 + c4] = wg[(size_t)(h * 256 + kt * 64 + kk) * 16 + c4];
    }
    __syncthreads();
    #pragma unroll 4
    for (int kk = 0; kk < 64; kk += 4) {
      float4 wv0 = wr4[(kk + 0) * 16 + fg];
      float4 wv1 = wr4[(kk + 1) * 16 + fg];
      float4 wv2 = wr4[(kk + 2) * 16 + fg];
      float4 wv3 = wr4[(kk + 3) * 16 + fg];
      #pragma unroll
      for (int q = 0; q < 4; ++q) {
        float4 xv = xr4[(rg * 4 + q) * 17 + (kk >> 2)];
        FMA4S(acc[q], xv.x, wv0);
        FMA4S(acc[q], xv.y, wv1);
        FMA4S(acc[q], xv.z, wv2);
        FMA4S(acc[q], xv.w, wv3);
      }
    }
  }

  // src/dst (log2e-scaled), shfl-reduced over the 16 fg lanes
  const float4* a4 = (const float4*)a;
  float4 as = a4[h * 32 + fg];
  float4 ad = a4[h * 32 + 16 + fg];
  as.x *= LOG2E; as.y *= LOG2E; as.z *= LOG2E; as.w *= LOG2E;
  ad.x *= LOG2E; ad.y *= LOG2E; ad.z *= LOG2E; ad.w *= LOG2E;
  #pragma unroll
  for (int q = 0; q < 4; ++q) {
    float s_ = acc[q].x * as.x + acc[q].y * as.y + acc[q].z * as.z + acc[q].w * as.w;
    float d_ = acc[q].x * ad.x + acc[q].y * ad.y + acc[q].z * ad.z + acc[q].w * ad.w;
    #pragma unroll
    for (int off = 1; off < 16; off <<= 1) {
      s_ += __shfl_xor(s_, off, 64);
      d_ += __shfl_xor(d_, off, 64);
    }
    if (fg == 0) {
      int r = rg * 4 + q;
      src[h * N + i0 + r] = s_;
      dst[h * N + i0 + r] = d_;
    }
  }

  // restage acc into xls (stride 68) for the B-fragment pack
  __syncthreads();
  #pragma unroll
  for (int q = 0; q < 4; ++q) {
    *(float4*)&xls[(rg * 4 + q) * 68 + fg * 4] = acc[q];
  }
  __syncthreads();

  {
    const int lane = t & 63;
    const int g    = t >> 6;        // col-group 0..3
    const int q    = lane >> 4;     // k-quad
    const int m    = lane & 15;     // B col within group
    short8* xb8 = (short8*)xtB;
    #pragma unroll
    for (int jcl = 0; jcl < 2; ++jcl) {
      int jc = (i0 >> 5) + jcl;
      short8 bv;
      #pragma unroll
      for (int r = 0; r < 8; ++r) {
        bv[r] = (short)f2bf(xls[(jcl * 32 + q * 8 + r) * 68 + g * 16 + m]);
      }
      xb8[((size_t)(h * 128 + jc) * 4 + g) * 64 + lane] = bv;
    }
  }
}

// ---------------------------------------------------------------------------
// Kernel 2: fused flash PV. grid (128, JSPLIT=8), block 256 (wave = head).
// R4 pipeline: prefetch distance 1 (no VGPR-forcing launch bound, no spill).
// Row sums via ones-B MFMA. Plain stores into js-partial buffers.
// ---------------------------------------------------------------------------
__global__ __launch_bounds__(256) void k_flash(const int* __restrict__ adj,
                                               const float* __restrict__ src,
                                               const float* __restrict__ dst,
                                               const short* __restrict__ xtB,
                                               float* __restrict__ accP,
                                               float* __restrict__ lP) {
  __shared__ __align__(16) float dls[HEADS][JLEN + 4];
  const int t    = threadIdx.x;
  const int lane = t & 63;
  const int h    = t >> 6;
  const int i0   = blockIdx.x * 32;
  const int js   = blockIdx.y;
  const int q    = lane >> 4;
  const int m    = lane & 15;
  const int koff = q * 8;
  const int jbase = js * JLEN;

  // stage dst slice: 4 heads x JLEN floats = 512 f4, 2 per thread
  #pragma unroll
  for (int s = 0; s < 2; ++s) {
    int idx = t + 256 * s;            // 0..511
    int hh = idx >> 7, j4 = idx & 127;
    *(float4*)&dls[hh][j4 * 4] = *(const float4*)(dst + (size_t)hh * N + jbase + j4 * 4);
  }

  float sv = (lane < 32) ? src[h * N + i0 + lane] : 0.f;
  const float s0 = __shfl(sv, m, 64);
  const float s1 = __shfl(sv, 16 + m, 64);
  __syncthreads();

  f32x4 acc0[4], acc1[4], accL0, accL1;
  #pragma unroll
  for (int g = 0; g < 4; ++g) { acc0[g] = (f32x4)(0.f); acc1[g] = (f32x4)(0.f); }
  accL0 = (f32x4)(0.f);
  accL1 = (f32x4)(0.f);

  short8 ones;
  #pragma unroll
  for (int r = 0; r < 8; ++r) ones[r] = (short)0x3F80;

  const int* arow0 = adj + (size_t)(i0 + m) * N + jbase + koff;
  const int* arow1 = adj + (size_t)(i0 + 16 + m) * N + jbase + koff;
  const short8* xbb = (const short8*)xtB + ((size_t)(h * 128 + js * NC) * 4) * 64 + lane;

#define LOADC(DA, DB, CIDX) do {                                           \
    const int* r0_ = arow0 + (CIDX) * 32;                                  \
    const int* r1_ = arow1 + (CIDX) * 32;                                  \
    DA[0] = *(const int4*)r0_;  DA[1] = *(const int4*)(r0_ + 4);           \
    DA[2] = *(const int4*)r1_;  DA[3] = *(const int4*)(r1_ + 4);           \
    const short8* bb_ = xbb + (size_t)(CIDX) * 256;                        \
    DB[0] = bb_[0]; DB[1] = bb_[64]; DB[2] = bb_[128]; DB[3] = bb_[192];   \
  } while (0)

  int4   cA[4], nA[4];
  short8 cB[4], nB[4];
  LOADC(cA, cB, 0);

  for (int c = 0; c < NC; ++c) {
    const int cn = (c + 1 < NC) ? c + 1 : c;
    LOADC(nA, nB, cn);

    const float* dp = &dls[h][c * 32 + koff];
    union { float4 v[2]; float f[8]; } du;
    du.v[0] = *(const float4*)dp;
    du.v[1] = *(const float4*)(dp + 4);

    const int* a0i = (const int*)&cA[0];
    const int* a1i = (const int*)&cA[2];
    int av0[4], av1[4];
    #pragma unroll
    for (int r2 = 0; r2 < 4; ++r2) {
      float e, el, p0a, p0b, p1a, p1b;
      e = s0 + du.f[2 * r2];     el = fmaxf(e, NEG * e);
      el = (a0i[2 * r2] > 0) ? el : -1e30f;      p0a = exp2_fast(el);
      e = s0 + du.f[2 * r2 + 1]; el = fmaxf(e, NEG * e);
      el = (a0i[2 * r2 + 1] > 0) ? el : -1e30f;  p0b = exp2_fast(el);
      e = s1 + du.f[2 * r2];     el = fmaxf(e, NEG * e);
      el = (a1i[2 * r2] > 0) ? el : -1e30f;      p1a = exp2_fast(el);
      e = s1 + du.f[2 * r2 + 1]; el = fmaxf(e, NEG * e);
      el = (a1i[2 * r2 + 1] > 0) ? el : -1e30f;  p1b = exp2_fast(el);
      av0[r2] = pack_bf2(p0a, p0b);
      av1[r2] = pack_bf2(p1a, p1b);
    }
    short8 af0 = __builtin_bit_cast(short8, *(int4*)av0);
    short8 af1 = __builtin_bit_cast(short8, *(int4*)av1);

    acc0[0] = __builtin_amdgcn_mfma_f32_16x16x32_bf16(af0, cB[0], acc0[0], 0, 0, 0);
    acc0[1] = __builtin_amdgcn_mfma_f32_16x16x32_bf16(af0, cB[1], acc0[1], 0, 0, 0);
    acc0[2] = __builtin_amdgcn_mfma_f32_16x16x32_bf16(af0, cB[2], acc0[2], 0, 0, 0);
    acc0[3] = __builtin_amdgcn_mfma_f32_16x16x32_bf16(af0, cB[3], acc0[3], 0, 0, 0);
    accL0   = __builtin_amdgcn_mfma_f32_16x16x32_bf16(af0, ones,  accL0,   0, 0, 0);
    acc1[0] = __builtin_amdgcn_mfma_f32_16x16x32_bf16(af1, cB[0], acc1[0], 0, 0, 0);
    acc1[1] = __builtin_amdgcn_mfma_f32_16x16x32_bf16(af1, cB[1], acc1[1], 0, 0, 0);
    acc1[2] = __builtin_amdgcn_mfma_f32_16x16x32_bf16(af1, cB[2], acc1[2], 0, 0, 0);
    acc1[3] = __builtin_amdgcn_mfma_f32_16x16x32_bf16(af1, cB[3], acc1[3], 0, 0, 0);
    accL1   = __builtin_amdgcn_mfma_f32_16x16x32_bf16(af1, ones,  accL1,   0, 0, 0);

    #pragma unroll
    for (int z = 0; z < 4; ++z) { cA[z] = nA[z]; cB[z] = nB[z]; }
  }
#undef LOADC

  // ---- epilogue: plain stores into js-partial buffers ----
  float* lp = lP + (size_t)js * (HEADS * N);
  if (m == 0) {
    #pragma unroll
    for (int reg = 0; reg < 4; ++reg) {
      lp[h * N + i0 + q * 4 + reg] = accL0[reg];
      lp[h * N + i0 + 16 + q * 4 + reg] = accL1[reg];
    }
  }

  float* ap = accP + (size_t)js * ((size_t)HEADS * N * OUT_F);
  #pragma unroll
  for (int reg = 0; reg < 4; ++reg) {
    int row0 = i0 + q * 4 + reg;
    int row1 = row0 + 16;
    #pragma unroll
    for (int g = 0; g < 4; ++g) {
      ap[((size_t)h * N + row0) * 64 + g * 16 + m] = acc0[g][reg];
      ap[((size_t)h * N + row1) * 64 + g * 16 + m] = acc1[g][reg];
    }
  }
}

// ---------------------------------------------------------------------------
// Kernel 3: out[i][h*64+f] = sum_js accP / sum_js lP
// ---------------------------------------------------------------------------
__global__ __launch_bounds__(256) void k_div(const float* __restrict__ accP,
                                             const float* __restrict__ lP,
                                             float* __restrict__ out) {
  int v = blockIdx.x * 256 + threadIdx.x;
  int col4 = v & 63;
  int i    = v >> 6;
  int h    = col4 >> 4;
  int fg   = col4 & 15;
  float4 s = make_float4(0.f, 0.f, 0.f, 0.f);
  float ls = 0.f;
  #pragma unroll
  for (int js = 0; js < JSPLIT; ++js) {
    const float4* a4p = (const float4*)(accP + (size_t)js * ((size_t)HEADS * N * OUT_F));
    float4 av = a4p[((size_t)h * N + i) * 16 + fg];
    s.x += av.x; s.y += av.y; s.z += av.z; s.w += av.w;
    ls += lP[(size_t)js * (HEADS * N) + h * N + i];
  }
  float il = 1.f / ls;
  ((float4*)out)[v] = make_float4(s.x * il, s.y * il, s.z * il, s.w * il);
}

extern "C" void kernel_launch(void* const* d_in, const int* in_sizes, int n_in,
                              void* d_out, int out_size, void* d_ws, size_t ws_size,
                              hipStream_t stream) {
  const float* x   = (const float*)d_in[0];
  const float* W   = (const float*)d_in[1];
  const float* a   = (const float*)d_in[2];
  const int*   adj = (const int*)d_in[3];
  float* out = (float*)d_out;

  float* ws   = (float*)d_ws;
  short* xtB  = (short*)ws;                                 // 2 MB
  float* src  = ws + 524288;                                // H*N
  float* dst  = src + HEADS * N;                            // H*N
  float* accP = dst + HEADS * N;                            // JSPLIT*H*N*64 = 33.5 MB
  float* lP   = accP + (size_t)JSPLIT * HEADS * N * OUT_F;  // JSPLIT*H*N

  k_xt<<<dim3(64, 4), 256, 0, stream>>>(x, W, a, xtB, src, dst);
  k_flash<<<dim3(N / 32, JSPLIT), 256, 0, stream>>>(adj, src, dst, xtB, accP, lP);
  k_div<<<dim3((N * OUT_F) / 256), 256, 0, stream>>>(accP, lP, out);
}